// Round 1
// baseline (304.980 us; speedup 1.0000x reference)
//
#include <hip/hip_runtime.h>
#include <cmath>

// SSIM: depthwise 11x11 gaussian convs (separable) fused into one tiled kernel.
// Layout: 48 planes (16 batch x 3 ch) of 512x512 f32; valid conv -> 502x502.

#define W 512
#define H 512
#define OW 502
#define OH 502
#define TILE 32
#define HALO 10
#define IN 42            // TILE + HALO
#define SPITCH 44        // padded pitch for sx/sy (multiple of 4, bank-friendly)
#define NVALID 12096192  // 48 * 502 * 502

struct Weights { float g[11]; };

__device__ __forceinline__ void fma4(float* a, float w, const float* v) {
    a[0] += w * v[0]; a[1] += w * v[1]; a[2] += w * v[2]; a[3] += w * v[3];
}

__global__ __launch_bounds__(256) void ssim_kernel(
    const float* __restrict__ x, const float* __restrict__ y,
    float* __restrict__ accum, Weights wt)
{
    __shared__ __align__(16) float sx[IN][SPITCH];
    __shared__ __align__(16) float sy[IN][SPITCH];
    __shared__ __align__(16) float hb[5][IN][TILE];

    const int tid = threadIdx.x;
    const int r0 = blockIdx.y * TILE;
    const int c0 = blockIdx.x * TILE;
    const size_t plane_off = (size_t)blockIdx.z * (W * H);
    const float* xp = x + plane_off;
    const float* yp = y + plane_off;

    // ---- Phase 0: stage halo'd input tile (42 rows x 44 cols, zero-padded OOB)
    for (int i = tid; i < IN * 11; i += 256) {
        int r = i / 11, q = i - r * 11;
        int gr = r0 + r, gc = c0 + 4 * q;
        float4 vx = make_float4(0.f, 0.f, 0.f, 0.f);
        float4 vy = make_float4(0.f, 0.f, 0.f, 0.f);
        if (gr < H) {
            if (gc + 3 < W) {
                vx = *(const float4*)&xp[(size_t)gr * W + gc];
                vy = *(const float4*)&yp[(size_t)gr * W + gc];
            } else if (gc < W) {
                const float* xr = &xp[(size_t)gr * W];
                const float* yr = &yp[(size_t)gr * W];
                float tx[4] = {0.f, 0.f, 0.f, 0.f}, ty[4] = {0.f, 0.f, 0.f, 0.f};
                #pragma unroll
                for (int e = 0; e < 4; e++) {
                    if (gc + e < W) { tx[e] = xr[gc + e]; ty[e] = yr[gc + e]; }
                }
                vx = make_float4(tx[0], tx[1], tx[2], tx[3]);
                vy = make_float4(ty[0], ty[1], ty[2], ty[3]);
            }
        }
        *(float4*)&sx[r][4 * q] = vx;
        *(float4*)&sy[r][4 * q] = vy;
    }
    __syncthreads();

    // ---- Phase 1: horizontal pass. 42 rows x 8 col-groups (4 outputs each).
    // For each group: read 16 consecutive x,y values (4 aligned float4 each),
    // produce 5 horizontally-convolved planes.
    for (int i = tid; i < IN * 8; i += 256) {
        int r = i >> 3;
        int cg = (i & 7) * 4;
        float xv[16], yv[16];
        #pragma unroll
        for (int q = 0; q < 4; q++) {
            float4 t1 = *(const float4*)&sx[r][cg + 4 * q];
            float4 t2 = *(const float4*)&sy[r][cg + 4 * q];
            xv[4 * q + 0] = t1.x; xv[4 * q + 1] = t1.y; xv[4 * q + 2] = t1.z; xv[4 * q + 3] = t1.w;
            yv[4 * q + 0] = t2.x; yv[4 * q + 1] = t2.y; yv[4 * q + 2] = t2.z; yv[4 * q + 3] = t2.w;
        }
        float m1[4] = {0.f, 0.f, 0.f, 0.f};
        float m2[4] = {0.f, 0.f, 0.f, 0.f};
        float e11[4] = {0.f, 0.f, 0.f, 0.f};
        float e22[4] = {0.f, 0.f, 0.f, 0.f};
        float e12[4] = {0.f, 0.f, 0.f, 0.f};
        #pragma unroll
        for (int k = 0; k < 11; k++) {
            float w = wt.g[k];
            #pragma unroll
            for (int j = 0; j < 4; j++) {
                float xa = xv[j + k], ya = yv[j + k];
                m1[j]  += w * xa;
                m2[j]  += w * ya;
                e11[j] += w * (xa * xa);
                e22[j] += w * (ya * ya);
                e12[j] += w * (xa * ya);
            }
        }
        *(float4*)&hb[0][r][cg] = make_float4(m1[0], m1[1], m1[2], m1[3]);
        *(float4*)&hb[1][r][cg] = make_float4(m2[0], m2[1], m2[2], m2[3]);
        *(float4*)&hb[2][r][cg] = make_float4(e11[0], e11[1], e11[2], e11[3]);
        *(float4*)&hb[3][r][cg] = make_float4(e22[0], e22[1], e22[2], e22[3]);
        *(float4*)&hb[4][r][cg] = make_float4(e12[0], e12[1], e12[2], e12[3]);
    }
    __syncthreads();

    // ---- Phase 2: vertical pass + SSIM. 64 strips of 4 rows x 4 cols.
    float lsum = 0.f;
    if (tid < 64) {
        int rs = tid >> 3;          // row strip 0..7 -> output rows 4*rs..4*rs+3
        int cg = (tid & 7) * 4;     // col group
        float acc[5][4][4];
        #pragma unroll
        for (int j = 0; j < 5; j++)
            #pragma unroll
            for (int rr = 0; rr < 4; rr++)
                #pragma unroll
                for (int e = 0; e < 4; e++) acc[j][rr][e] = 0.f;

        #pragma unroll
        for (int t = 0; t < 14; t++) {
            int row = (rs << 2) + t;
            float vv[5][4];
            #pragma unroll
            for (int j = 0; j < 5; j++) {
                float4 v = *(const float4*)&hb[j][row][cg];
                vv[j][0] = v.x; vv[j][1] = v.y; vv[j][2] = v.z; vv[j][3] = v.w;
            }
            #pragma unroll
            for (int rr = 0; rr < 4; rr++) {
                int k = t - rr;
                if (k >= 0 && k <= 10) {
                    float w = wt.g[k];
                    #pragma unroll
                    for (int j = 0; j < 5; j++) fma4(acc[j][rr], w, vv[j]);
                }
            }
        }

        const float C1 = 1e-4f;   // (0.01*1)^2
        const float C2 = 9e-4f;   // (0.03*1)^2
        #pragma unroll
        for (int rr = 0; rr < 4; rr++) {
            int orow = r0 + (rs << 2) + rr;
            if (orow < OH) {
                #pragma unroll
                for (int e = 0; e < 4; e++) {
                    int ocol = c0 + cg + e;
                    if (ocol < OW) {
                        float mu1 = acc[0][rr][e];
                        float mu2 = acc[1][rr][e];
                        float ex2 = acc[2][rr][e];
                        float ey2 = acc[3][rr][e];
                        float exy = acc[4][rr][e];
                        float mu12 = mu1 * mu2;
                        float mu1s = mu1 * mu1;
                        float mu2s = mu2 * mu2;
                        float s11 = ex2 - mu1s;
                        float s22 = ey2 - mu2s;
                        float s12 = exy - mu12;
                        float num = (2.f * mu12 + C1) * (2.f * s12 + C2);
                        float den = (mu1s + mu2s + C1) * (s11 + s22 + C2);
                        lsum += num / den;
                    }
                }
            }
        }
    }

    // ---- Reduce: only wave 0 holds nonzero lsum.
    #pragma unroll
    for (int off = 32; off > 0; off >>= 1) lsum += __shfl_down(lsum, off, 64);
    if (tid == 0) unsafeAtomicAdd(accum, lsum);
}

__global__ void finalize_kernel(const float* __restrict__ accum, float* __restrict__ out) {
    out[0] = accum[0] * (1.0f / (float)NVALID);
}

extern "C" void kernel_launch(void* const* d_in, const int* in_sizes, int n_in,
                              void* d_out, int out_size, void* d_ws, size_t ws_size,
                              hipStream_t stream) {
    const float* x = (const float*)d_in[0];
    const float* y = (const float*)d_in[1];
    float* accum = (float*)d_ws;
    float* out = (float*)d_out;

    // Gaussian window, computed in double like the numpy reference, cast to f32.
    Weights wt;
    {
        double g[11], s = 0.0;
        for (int i = 0; i < 11; i++) {
            double d = (double)(i - 5);
            g[i] = exp(-(d * d) / (2.0 * 1.5 * 1.5));
            s += g[i];
        }
        for (int i = 0; i < 11; i++) wt.g[i] = (float)(g[i] / s);
    }

    hipMemsetAsync(accum, 0, sizeof(float), stream);
    dim3 grid(16, 16, 48);
    ssim_kernel<<<grid, 256, 0, stream>>>(x, y, accum, wt);
    finalize_kernel<<<1, 1, 0, stream>>>(accum, out);
}